// Round 7
// baseline (382.948 us; speedup 1.0000x reference)
//
#include <hip/hip_runtime.h>
#include <math.h>

#define L2E 1.44269504088896340736f   // log2(e)
#define LN2 0.69314718055994530942f   // ln(2)

#if __has_builtin(__builtin_amdgcn_exp2f)
__device__ __forceinline__ float fexp2(float x)  { return __builtin_amdgcn_exp2f(x); }
#else
__device__ __forceinline__ float fexp2(float x)  { return __exp2f(x); }
#endif
#if __has_builtin(__builtin_amdgcn_logf)
__device__ __forceinline__ float flog2(float x)  { return __builtin_amdgcn_logf(x); }
#else
__device__ __forceinline__ float flog2(float x)  { return __log2f(x); }
#endif

// Full row contribution (tail path only).
__device__ __forceinline__ float row_contrib_full(
    const float* __restrict__ pb, const float4* __restrict__ pt4,
    const float4* __restrict__ ps4, const float* __restrict__ tb,
    const float4* __restrict__ tt4, const int* __restrict__ ts,
    const float* __restrict__ psf, int row)
{
    float  xb = pb[row], yb = tb[row];
    int    lab = ts[row];
    float4 xt = pt4[row], yt = tt4[row];
    size_t b = (size_t)row * 4;
    float4 r0 = ps4[b+0], r1 = ps4[b+1], r2 = ps4[b+2], r3 = ps4[b+3];
    float vlab = psf[(size_t)row * 16 + lab];
    float v[16] = { r0.x,r0.y,r0.z,r0.w, r1.x,r1.y,r1.z,r1.w,
                    r2.x,r2.y,r2.z,r2.w, r3.x,r3.y,r3.z,r3.w };
    float s = 0.0f;
    for (int j = 0; j < 16; ++j) s += fexp2(v[j] * L2E);
    float g = fexp2(xb * L2E);
    float p = (1.0f+fexp2(xt.x*L2E))*(1.0f+fexp2(xt.y*L2E))
            * (1.0f+fexp2(xt.z*L2E))*(1.0f+fexp2(xt.w*L2E));
    float c = LN2 * (flog2(s * (1.0f+g)) + 0.25f * flog2(p));
    float dot = xt.x*yt.x + xt.y*yt.y + xt.z*yt.z + xt.w*yt.w;
    c = c - vlab - yb*xb - 0.25f*dot;
    bool bin_c  = (xb >= 0.0f);
    bool type_c = fmaxf(fmaxf(xt.x,xt.y), fmaxf(xt.z,xt.w)) >= 0.0f;
    float mr = v[1];
    for (int j = 2; j < 16; ++j) mr = fmaxf(mr, v[j]);
    bool src_c = (mr > v[0]);
    c += (bin_c != type_c) ? 1.0f : 0.0f;
    c += (bin_c != src_c)  ? 1.0f : 0.0f;
    return c;
}

// R6 kernel verbatim — best measured variant (86.4 us).
__global__ __launch_bounds__(256) void multitask_loss_kernel(
    const float*  __restrict__ pb,
    const float4* __restrict__ pt4,
    const float4* __restrict__ ps4,
    const float*  __restrict__ tb,
    const float4* __restrict__ tt4,
    const int*    __restrict__ ts,
    const float*  __restrict__ psf,
    float*        __restrict__ partials)
{
    const int tid = threadIdx.x;
    const int row = blockIdx.x * 256 + tid;

    float  xb = pb[row], yb = tb[row];
    int    lab = ts[row];
    float4 xt = pt4[row], yt = tt4[row];
    size_t b = (size_t)row * 4;
    float4 r0 = ps4[b+0], r1 = ps4[b+1], r2 = ps4[b+2], r3 = ps4[b+3];
    float  vlab = psf[(size_t)row * 16 + lab];

    float v[16] = { r0.x,r0.y,r0.z,r0.w, r1.x,r1.y,r1.z,r1.w,
                    r2.x,r2.y,r2.z,r2.w, r3.x,r3.y,r3.z,r3.w };

    float e[16];
    #pragma unroll
    for (int j = 0; j < 16; ++j) e[j] = fexp2(v[j] * L2E);
    #pragma unroll
    for (int st = 8; st >= 1; st >>= 1)
        #pragma unroll
        for (int j = 0; j < st; ++j) e[j] += e[j + st];
    float s = e[0];

    float g  = fexp2(xb * L2E);
    float s2 = s * (1.0f + g);

    float f0 = fexp2(xt.x * L2E), f1 = fexp2(xt.y * L2E);
    float f2 = fexp2(xt.z * L2E), f3 = fexp2(xt.w * L2E);
    float p  = ((1.0f+f0)*(1.0f+f1)) * ((1.0f+f2)*(1.0f+f3));

    float c = LN2 * (flog2(s2) + 0.25f * flog2(p));

    float dot = xt.x*yt.x + xt.y*yt.y + xt.z*yt.z + xt.w*yt.w;
    c = c - vlab - yb*xb - 0.25f*dot;

    bool bin_c  = (xb >= 0.0f);
    bool type_c = fmaxf(fmaxf(xt.x, xt.y), fmaxf(xt.z, xt.w)) >= 0.0f;
    float m01 = fmaxf(v[1],  v[2]),  m23 = fmaxf(v[3],  v[4]);
    float m45 = fmaxf(v[5],  v[6]),  m67 = fmaxf(v[7],  v[8]);
    float m89 = fmaxf(v[9],  v[10]), mab = fmaxf(v[11], v[12]);
    float mcd = fmaxf(v[13], v[14]);
    float mr  = fmaxf(fmaxf(fmaxf(m01, m23), fmaxf(m45, m67)),
                      fmaxf(fmaxf(m89, mab), fmaxf(mcd, v[15])));
    bool src_c = (mr > v[0]);

    unsigned long long mb = __ballot(bin_c);
    unsigned long long mt = __ballot(type_c);
    unsigned long long ms = __ballot(src_c);
    int pen = __popcll(mb ^ mt) + __popcll(mb ^ ms);

    #pragma unroll
    for (int off = 32; off > 0; off >>= 1)
        c += __shfl_down(c, off, 64);

    __shared__ float wsum[4];
    const int lane = tid & 63;
    const int wave = tid >> 6;
    if (lane == 0) wsum[wave] = c + (float)pen;
    __syncthreads();
    if (tid == 0)
        partials[blockIdx.x] = wsum[0] + wsum[1] + wsum[2] + wsum[3];
}

__global__ __launch_bounds__(256) void reduce_kernel(
    const float* __restrict__ partials, int nblocks,
    const float*  __restrict__ pb,  const float4* __restrict__ pt4,
    const float4* __restrict__ ps4, const float*  __restrict__ tb,
    const float4* __restrict__ tt4, const int*    __restrict__ ts,
    const float*  __restrict__ psf,
    int n_main, int B, float* __restrict__ out, double invB)
{
    double s = 0.0;
    for (int i = threadIdx.x; i < nblocks; i += 256)
        s += (double)partials[i];
    for (int r = n_main + threadIdx.x; r < B; r += 256)
        s += (double)row_contrib_full(pb, pt4, ps4, tb, tt4, ts, psf, r);

    #pragma unroll
    for (int off = 32; off > 0; off >>= 1)
        s += __shfl_down(s, off, 64);

    __shared__ double wsum[4];
    int lane = threadIdx.x & 63;
    int wave = threadIdx.x >> 6;
    if (lane == 0) wsum[wave] = s;
    __syncthreads();
    if (threadIdx.x == 0)
        out[0] = (float)((wsum[0] + wsum[1] + wsum[2] + wsum[3]) * invB);
}

// ---- DIAGNOSTIC: 6-pass streaming-read probe over ps (6 x 134 MB = 805 MB).
// Sized to ALWAYS rank in rocprof top-5 (>=103 us even at 7.8 TB/s), so this
// round yields a trustworthy per-dispatch dur/hbm_gbps/FETCH_SIZE for the
// true in-situ streaming ceiling on this exact (L3-warm) data.
__global__ __launch_bounds__(256) void bw_probe_kernel(
    const float4* __restrict__ src, int n4, float* __restrict__ probe_out)
{
    const int stride = gridDim.x * 256;
    float4 a0 = {0,0,0,0}, a1 = {0,0,0,0}, a2 = {0,0,0,0}, a3 = {0,0,0,0};
    for (int pass = 0; pass < 6; ++pass) {
        int i = blockIdx.x * 256 + threadIdx.x;
        for (; i + 3 * stride < n4; i += 4 * stride) {
            float4 v0 = src[i];
            float4 v1 = src[i + stride];
            float4 v2 = src[i + 2 * stride];
            float4 v3 = src[i + 3 * stride];
            a0.x += v0.x; a0.y += v0.y; a0.z += v0.z; a0.w += v0.w;
            a1.x += v1.x; a1.y += v1.y; a1.z += v1.z; a1.w += v1.w;
            a2.x += v2.x; a2.y += v2.y; a2.z += v2.z; a2.w += v2.w;
            a3.x += v3.x; a3.y += v3.y; a3.z += v3.z; a3.w += v3.w;
        }
        for (; i < n4; i += stride) {
            float4 v = src[i];
            a0.x += v.x; a0.y += v.y; a0.z += v.z; a0.w += v.w;
        }
    }
    float s = (a0.x + a0.y + a0.z + a0.w) + (a1.x + a1.y + a1.z + a1.w)
            + (a2.x + a2.y + a2.z + a2.w) + (a3.x + a3.y + a3.z + a3.w);
    #pragma unroll
    for (int off = 32; off > 0; off >>= 1)
        s += __shfl_down(s, off, 64);
    if ((threadIdx.x & 63) == 0)
        probe_out[blockIdx.x * 4 + (threadIdx.x >> 6)] = s;
}

extern "C" void kernel_launch(void* const* d_in, const int* in_sizes, int n_in,
                              void* d_out, int out_size, void* d_ws, size_t ws_size,
                              hipStream_t stream) {
    const float*  pb  = (const float*)d_in[0];
    const float4* pt4 = (const float4*)d_in[1];
    const float4* ps4 = (const float4*)d_in[2];
    const float*  psf = (const float*)d_in[2];
    const float*  tb  = (const float*)d_in[3];
    const float4* tt4 = (const float4*)d_in[4];
    const int*    ts  = (const int*)d_in[5];
    int B = in_sizes[0];                       // 2097152 = 8192 * 256

    float* partials = (float*)d_ws;            // [8192]

    int grid   = B / 256;
    int n_main = grid * 256;

    multitask_loss_kernel<<<grid, 256, 0, stream>>>(pb, pt4, ps4, tb, tt4, ts,
                                                    psf, partials);
    reduce_kernel<<<1, 256, 0, stream>>>(partials, grid,
                                         pb, pt4, ps4, tb, tt4, ts, psf,
                                         n_main, B, (float*)d_out,
                                         1.0 / (double)B);
    // Probe runs AFTER reduce consumed partials; reuses that d_ws region
    // (2048 blocks x 4 waves = 8192 floats). Does not touch d_out.
    bw_probe_kernel<<<2048, 256, 0, stream>>>(ps4, B * 4, partials);
}

// Round 8
// 259.373 us; speedup vs baseline: 1.4764x; 1.4764x over previous
//
#include <hip/hip_runtime.h>
#include <math.h>

#define L2E 1.44269504088896340736f   // log2(e)
#define LN2 0.69314718055994530942f   // ln(2)
#define G_BLOCKS 2048

#if __has_builtin(__builtin_amdgcn_exp2f)
__device__ __forceinline__ float fexp2(float x)  { return __builtin_amdgcn_exp2f(x); }
#else
__device__ __forceinline__ float fexp2(float x)  { return __exp2f(x); }
#endif
#if __has_builtin(__builtin_amdgcn_logf)
__device__ __forceinline__ float flog2(float x)  { return __builtin_amdgcn_logf(x); }
#else
__device__ __forceinline__ float flog2(float x)  { return __log2f(x); }
#endif

// Full row contribution (tail path only — empty at B=2^21).
__device__ __forceinline__ float row_contrib_full(
    const float* __restrict__ pb, const float4* __restrict__ pt4,
    const float4* __restrict__ ps4, const float* __restrict__ tb,
    const float4* __restrict__ tt4, const int* __restrict__ ts,
    const float* __restrict__ psf, int row)
{
    float  xb = pb[row], yb = tb[row];
    int    lab = ts[row];
    float4 xt = pt4[row], yt = tt4[row];
    size_t b = (size_t)row * 4;
    float4 r0 = ps4[b+0], r1 = ps4[b+1], r2 = ps4[b+2], r3 = ps4[b+3];
    float vlab = psf[(size_t)row * 16 + lab];
    float v[16] = { r0.x,r0.y,r0.z,r0.w, r1.x,r1.y,r1.z,r1.w,
                    r2.x,r2.y,r2.z,r2.w, r3.x,r3.y,r3.z,r3.w };
    float s = 0.0f;
    for (int j = 0; j < 16; ++j) s += fexp2(v[j] * L2E);
    float g = fexp2(xb * L2E);
    float p = (1.0f+fexp2(xt.x*L2E))*(1.0f+fexp2(xt.y*L2E))
            * (1.0f+fexp2(xt.z*L2E))*(1.0f+fexp2(xt.w*L2E));
    float c = LN2 * (flog2(s * (1.0f+g)) + 0.25f * flog2(p));
    float dot = xt.x*yt.x + xt.y*yt.y + xt.z*yt.z + xt.w*yt.w;
    c = c - vlab - yb*xb - 0.25f*dot;
    bool bin_c  = (xb >= 0.0f);
    bool type_c = fmaxf(fmaxf(xt.x,xt.y), fmaxf(xt.z,xt.w)) >= 0.0f;
    float mr = v[1];
    for (int j = 2; j < 16; ++j) mr = fmaxf(mr, v[j]);
    bool src_c = (mr > v[0]);
    c += (bin_c != type_c) ? 1.0f : 0.0f;
    c += (bin_c != src_c)  ? 1.0f : 0.0f;
    return c;
}

// Probe-parity main kernel: EVERY load is unit-stride 16B/4B-per-lane
// coalesced (16/4 lines per instruction, fully consumed). ps is read with
// 4-lanes-per-row layout; CE assembled with 4-lane shfl reductions.
__global__ __launch_bounds__(256) void multitask_loss_kernel(
    const float*  __restrict__ pb,
    const float4* __restrict__ pt4,
    const float4* __restrict__ ps4,
    const float*  __restrict__ tb,
    const float4* __restrict__ tt4,
    const int*    __restrict__ ts,
    int iters,
    float*        __restrict__ partials)
{
    const int tid  = threadIdx.x;
    const int lane = tid & 63;
    const int wave = tid >> 6;
    const int qz   = lane & 3;     // my quarter within the row-group
    const int grp  = lane >> 2;    // group id 0..15

    float acc = 0.0f;

    for (int it = 0; it < iters; ++it) {
        const size_t R = ((size_t)it * G_BLOCKS + blockIdx.x) * 256
                       + (size_t)wave * 64;       // wave's 64-row base
        const int row = (int)R + lane;

        // ---- owner-lane streams (lane = row): all unit-stride coalesced ----
        float  xb = pb[row];
        float  yb = tb[row];
        int    lab = ts[row];
        float4 xt = pt4[row];
        float4 yt = tt4[row];

        // ---- ps: 4 coalesced dwordx4; q[j] = quarter qz of row R+16j+grp ----
        size_t pbase = R * 4;
        float4 q0 = ps4[pbase +   0 + lane];
        float4 q1 = ps4[pbase +  64 + lane];
        float4 q2 = ps4[pbase + 128 + lane];
        float4 q3 = ps4[pbase + 192 + lane];

        // ---- own-row binary + type part (R6 math) ----
        float g  = fexp2(xb * L2E);
        float f0 = fexp2(xt.x*L2E), f1 = fexp2(xt.y*L2E);
        float f2 = fexp2(xt.z*L2E), f3 = fexp2(xt.w*L2E);
        float p  = ((1.0f+f0)*(1.0f+f1)) * ((1.0f+f2)*(1.0f+f3));
        float dot = xt.x*yt.x + xt.y*yt.y + xt.z*yt.z + xt.w*yt.w;
        float c = LN2 * (flog2(1.0f+g) + 0.25f*flog2(p)) - yb*xb - 0.25f*dot;
        bool bin_c  = (xb >= 0.0f);
        bool type_c = fmaxf(fmaxf(xt.x,xt.y), fmaxf(xt.z,xt.w)) >= 0.0f;

        // ---- group-space CE; route results back to owner lanes ----
        float S_own = 1.0f, V_own = 0.0f;
        #pragma unroll
        for (int j = 0; j < 4; ++j) {
            float4 qj = (j==0) ? q0 : (j==1) ? q1 : (j==2) ? q2 : q3;

            float e = fexp2(qj.x*L2E) + fexp2(qj.y*L2E)
                    + fexp2(qj.z*L2E) + fexp2(qj.w*L2E);

            float m4 = fmaxf(fmaxf(qj.x,qj.y), fmaxf(qj.z,qj.w));
            float m3 = fmaxf(fmaxf(qj.y,qj.z), qj.w);
            float Mloc = (qz == 0) ? m3 : m4;      // exclude global elem 0

            int labj = __shfl(lab, 16*j + grp, 64);       // label of group's row
            float sA  = (labj & 1) ? qj.y : qj.x;
            float sB  = (labj & 1) ? qj.w : qj.z;
            float sel = (labj & 2) ? sB : sA;             // v[4*qz + (labj&3)]
            float vlab = __shfl(sel, (lane & ~3) + (labj >> 2), 64); // v[labj]

            float t = e + __shfl_xor(e, 1, 64);
            float S = t + __shfl_xor(t, 2, 64);           // sum of 16 exps
            float u = fmaxf(Mloc, __shfl_xor(Mloc, 1, 64));
            float M = fmaxf(u, __shfl_xor(u, 2, 64));     // max(v[1..15])
            float v0 = __shfl(qj.x, lane & ~3, 64);       // v[0]

            float Ssgn = (M > v0) ? -S : S;   // pack src_c into sign (S>0 always)

            float Sb = __shfl(Ssgn, (lane & 15) * 4, 64); // route to owners
            float Vb = __shfl(vlab, (lane & 15) * 4, 64);
            if ((lane >> 4) == j) { S_own = Sb; V_own = Vb; }
        }

        bool src_c = (S_own < 0.0f);
        c += LN2 * flog2(fabsf(S_own)) - V_own;           // CE: lse - v[lab]
        c += (bin_c != type_c) ? 1.0f : 0.0f;
        c += (bin_c != src_c)  ? 1.0f : 0.0f;
        acc += c;
    }

    // ---- wave reduce + block partial ----
    #pragma unroll
    for (int off = 32; off > 0; off >>= 1)
        acc += __shfl_down(acc, off, 64);

    __shared__ float wsum[4];
    if (lane == 0) wsum[wave] = acc;
    __syncthreads();
    if (tid == 0)
        partials[blockIdx.x] = wsum[0] + wsum[1] + wsum[2] + wsum[3];
}

__global__ __launch_bounds__(256) void reduce_kernel(
    const float* __restrict__ partials, int nblocks,
    const float*  __restrict__ pb,  const float4* __restrict__ pt4,
    const float4* __restrict__ ps4, const float*  __restrict__ tb,
    const float4* __restrict__ tt4, const int*    __restrict__ ts,
    const float*  __restrict__ psf,
    int n_main, int B, float* __restrict__ out, double invB)
{
    double s = 0.0;
    for (int i = threadIdx.x; i < nblocks; i += 256)
        s += (double)partials[i];
    for (int r = n_main + threadIdx.x; r < B; r += 256)
        s += (double)row_contrib_full(pb, pt4, ps4, tb, tt4, ts, psf, r);

    #pragma unroll
    for (int off = 32; off > 0; off >>= 1)
        s += __shfl_down(s, off, 64);

    __shared__ double wsum[4];
    int lane = threadIdx.x & 63;
    int wave = threadIdx.x >> 6;
    if (lane == 0) wsum[wave] = s;
    __syncthreads();
    if (threadIdx.x == 0)
        out[0] = (float)((wsum[0] + wsum[1] + wsum[2] + wsum[3]) * invB);
}

extern "C" void kernel_launch(void* const* d_in, const int* in_sizes, int n_in,
                              void* d_out, int out_size, void* d_ws, size_t ws_size,
                              hipStream_t stream) {
    const float*  pb  = (const float*)d_in[0];
    const float4* pt4 = (const float4*)d_in[1];
    const float4* ps4 = (const float4*)d_in[2];
    const float*  psf = (const float*)d_in[2];
    const float*  tb  = (const float*)d_in[3];
    const float4* tt4 = (const float4*)d_in[4];
    const int*    ts  = (const int*)d_in[5];
    int B = in_sizes[0];                       // 2097152 = 2048 * 256 * 4

    float* partials = (float*)d_ws;            // [G_BLOCKS] fully overwritten

    int iters  = B / (G_BLOCKS * 256);         // 4
    int n_main = iters * G_BLOCKS * 256;       // tail (empty here) in reduce

    multitask_loss_kernel<<<G_BLOCKS, 256, 0, stream>>>(pb, pt4, ps4, tb, tt4,
                                                        ts, iters, partials);
    reduce_kernel<<<1, 256, 0, stream>>>(partials, G_BLOCKS,
                                         pb, pt4, ps4, tb, tt4, ts, psf,
                                         n_main, B, (float*)d_out,
                                         1.0 / (double)B);
}